// Round 12
// baseline (717.688 us; speedup 1.0000x reference)
//
#include <hip/hip_runtime.h>

// Chamfer forward: dist0[i] = min_j ||pc0[i]-pc1[j]||^2 ; out = mean(dist0[dist0<=2])
// N = M = 65536 i.i.d. N(0,1)^3 points, fp32.
// Spatial grid (counting sort), 32^3 cells, h=0.25 over [-4,4]^3 (clamp = contraction,
// ring bound stays valid). Both clouds sorted by cell.
// ROUND 12: block-per-cell query with LDS-staged 27-cell neighborhood. R9-R11 were
// ~90% latency-stalled (VALUBusy*dur ~19us vs 3.6us true pair math): per-query
// scattered L2 chains. Now each block stages its neighborhood ONCE (coalesced CSR
// segments, avg ~620 pts, max ~1750 < CAP 2048 = 32KB LDS), then wave-per-query
// lane-strided LDS scans. Ring expansion (best > H^2, ~2% of queries) uses the
// global CSR path. Finalize fused via 64 spread buckets + done counter.

constexpr int   NPTS  = 65536;
constexpr int   G     = 32;
constexpr int   NC    = G * G * G;   // 32768 cells
constexpr float H     = 0.25f;
constexpr float ORG   = -4.0f;
constexpr float INVH  = 4.0f;
constexpr int   BLOCK = 256;
constexpr int   CAP   = 2048;        // LDS staging capacity (float4 = 32 KB)

__device__ __forceinline__ int cellOf(float x) {
  int c = (int)floorf((x - ORG) * INVH);
  return min(max(c, 0), G - 1);
}

__global__ __launch_bounds__(BLOCK) void count_kernel(
    const float* __restrict__ pc0, const float* __restrict__ pc1,
    unsigned* __restrict__ counts0, unsigned* __restrict__ counts1) {
  const int gid = blockIdx.x * BLOCK + threadIdx.x;
  const float* p; unsigned* cnt; int i;
  if (gid < NPTS) { p = pc1; cnt = counts1; i = gid; }
  else            { p = pc0; cnt = counts0; i = gid - NPTS; }
  const float x = p[3 * i], y = p[3 * i + 1], z = p[3 * i + 2];
  const int cid = (cellOf(z) * G + cellOf(y)) * G + cellOf(x);
  atomicAdd(&cnt[cid], 1u);
}

// Exclusive scan of NC elements, shfl-based (1024 threads x 32 cells each).
__device__ void scan_one(const unsigned* __restrict__ counts,
                         unsigned* __restrict__ starts,
                         unsigned* __restrict__ cursor,
                         unsigned* waveTot /* [16] */) {
  const int tid = threadIdx.x;
  constexpr int PER = NC / 1024;   // 32
  const int base = tid * PER;
  unsigned loc[PER];
  unsigned run = 0;
  for (int j = 0; j < PER; ++j) { loc[j] = counts[base + j]; run += loc[j]; }
  unsigned inc = run;
  for (int off = 1; off < 64; off <<= 1) {
    const unsigned v = __shfl_up(inc, off, 64);
    if ((tid & 63) >= off) inc += v;
  }
  if ((tid & 63) == 63) waveTot[tid >> 6] = inc;
  __syncthreads();
  if (tid < 16) {
    unsigned w = waveTot[tid];
    for (int off = 1; off < 16; off <<= 1) {
      const unsigned v = __shfl_up(w, off, 16);
      if (tid >= off) w += v;
    }
    waveTot[tid] = w;
  }
  __syncthreads();
  const unsigned waveOff = (tid >> 6) == 0 ? 0u : waveTot[(tid >> 6) - 1];
  unsigned r = waveOff + inc - run;
  for (int j = 0; j < PER; ++j) { starts[base + j] = r; cursor[base + j] = r; r += loc[j]; }
  if (tid == 1023) starts[NC] = r;
}

__global__ __launch_bounds__(1024) void scan_kernel(
    const unsigned* __restrict__ counts0, unsigned* __restrict__ starts0,
    unsigned* __restrict__ cursor0,
    const unsigned* __restrict__ counts1, unsigned* __restrict__ starts1,
    unsigned* __restrict__ cursor1) {
  __shared__ unsigned waveTot[16];
  if (blockIdx.x == 0) scan_one(counts1, starts1, cursor1, waveTot);
  else                 scan_one(counts0, starts0, cursor0, waveTot);
}

__global__ __launch_bounds__(BLOCK) void scatter_kernel(
    const float* __restrict__ pc0, const float* __restrict__ pc1,
    unsigned* __restrict__ cursor0, unsigned* __restrict__ cursor1,
    float4* __restrict__ q, float4* __restrict__ s) {
  const int gid = blockIdx.x * BLOCK + threadIdx.x;
  const float* p; unsigned* cur; float4* dst; int i;
  if (gid < NPTS) { p = pc1; cur = cursor1; dst = s; i = gid; }
  else            { p = pc0; cur = cursor0; dst = q; i = gid - NPTS; }
  const float x = p[3 * i], y = p[3 * i + 1], z = p[3 * i + 2];
  const int cid = (cellOf(z) * G + cellOf(y)) * G + cellOf(x);
  const unsigned pos = atomicAdd(&cur[cid], 1u);
  dst[pos] = make_float4(x, y, z, 0.f);
}

// Wave-cooperative ring expansion over the global CSR (rare: ~2% of queries).
__device__ float expand_rings(const float4 p, int cx, int cy, int cz, float best,
                              int lane, const unsigned* __restrict__ starts,
                              const float4* __restrict__ s) {
  auto scanRow = [&](int zz, int yy, int x0, int x1) {
    if (zz < 0 || zz >= G || yy < 0 || yy >= G) return;
    x0 = max(x0, 0); x1 = min(x1, G - 1);
    if (x0 > x1) return;
    const int rb = (zz * G + yy) * G;
    unsigned j = starts[rb + x0] + lane;
    const unsigned e = starts[rb + x1 + 1];
    for (; j < e; j += 64) {
      const float4 c = s[j];
      const float dx = p.x - c.x, dy = p.y - c.y, dz = p.z - c.z;
      best = fminf(best, fmaf(dx, dx, fmaf(dy, dy, dz * dz)));
    }
  };
  for (int r = 2; r <= G; ++r) {
    const float cov = H * (float)(r - 1);
    if (best <= cov * cov) break;
    for (int dz = -r; dz <= r; ++dz) {
      const int zz = cz + dz;
      if (zz < 0 || zz >= G) continue;
      if (dz == -r || dz == r) {
        for (int dy = -r; dy <= r; ++dy)
          scanRow(zz, cy + dy, cx - r, cx + r);
      } else {
        scanRow(zz, cy - r, cx - r, cx + r);
        scanRow(zz, cy + r, cx - r, cx + r);
        for (int dy = -r + 1; dy <= r - 1; ++dy) {
          scanRow(zz, cy + dy, cx - r, cx - r);
          scanRow(zz, cy + dy, cx + r, cx + r);
        }
      }
    }
    for (int o = 32; o; o >>= 1) best = fminf(best, __shfl_xor(best, o, 64));
  }
  return best;
}

// One block per cell: stage 27-cell neighborhood in LDS, wave-per-query scan.
__global__ __launch_bounds__(BLOCK) void query_cell_kernel(
    const float4* __restrict__ q, const unsigned* __restrict__ qstarts,
    const float4* __restrict__ s, const unsigned* __restrict__ sstarts,
    float* __restrict__ bkt /* 128 floats: 64 (sum,count) buckets */,
    unsigned* __restrict__ done, float* __restrict__ out) {
  __shared__ float4 buf[CAP];
  __shared__ float wsum[BLOCK / 64], wcnt[BLOCK / 64];
  const int cid = blockIdx.x;
  const unsigned qs = qstarts[cid], qe = qstarts[cid + 1];

  if (qe > qs) {   // block-uniform branch
    const int cx = cid & (G - 1), cy = (cid >> 5) & (G - 1), cz = cid >> 10;
    const int xa = max(cx - 1, 0), xb = min(cx + 1, G - 1);
    unsigned segS[9], segL[9], off[9], total = 0;
#pragma unroll
    for (int rr = 0; rr < 9; ++rr) {
      const int zz = cz + rr / 3 - 1, yy = cy + rr % 3 - 1;
      const bool ok = (zz >= 0) && (zz < G) && (yy >= 0) && (yy < G);
      const int rb = ok ? (zz * G + yy) * G : 0;
      const unsigned s0 = ok ? sstarts[rb + xa] : 0u;
      const unsigned s1 = ok ? sstarts[rb + xb + 1] : 0u;
      segS[rr] = s0; segL[rr] = s1 - s0; off[rr] = total; total += s1 - s0;
    }
    const int wid = threadIdx.x >> 6, lane = threadIdx.x & 63;
    float v = 0.f, c = 0.f;

    if (total <= (unsigned)CAP) {   // block-uniform
      // coalesced cooperative staging of the 9 CSR segments
#pragma unroll
      for (int rr = 0; rr < 9; ++rr)
        for (unsigned t = threadIdx.x; t < segL[rr]; t += BLOCK)
          buf[off[rr] + t] = s[segS[rr] + t];
      __syncthreads();

      for (unsigned qi = qs + wid; qi < qe; qi += BLOCK / 64) {
        const float4 p = q[qi];   // wave-uniform -> broadcast
        float best = 3.4e38f;
        for (unsigned t = lane; t < total; t += 64) {
          const float4 cd = buf[t];
          const float dx = p.x - cd.x, dy = p.y - cd.y, dz = p.z - cd.z;
          best = fminf(best, fmaf(dx, dx, fmaf(dy, dy, dz * dz)));
        }
        for (int o = 32; o; o >>= 1) best = fminf(best, __shfl_xor(best, o, 64));
        if (best > H * H)   // coverage radius after rings 0..1 is H
          best = expand_rings(p, cx, cy, cz, best, lane, sstarts, s);
        if (lane == 0 && best <= 2.0f) { v += best; c += 1.0f; }
      }
    } else {   // overflow fallback: global row scans (not expected at N=65536)
      for (unsigned qi = qs + wid; qi < qe; qi += BLOCK / 64) {
        const float4 p = q[qi];
        float best = 3.4e38f;
#pragma unroll
        for (int rr = 0; rr < 9; ++rr) {
          for (unsigned t = segS[rr] + lane; t < segS[rr] + segL[rr]; t += 64) {
            const float4 cd = s[t];
            const float dx = p.x - cd.x, dy = p.y - cd.y, dz = p.z - cd.z;
            best = fminf(best, fmaf(dx, dx, fmaf(dy, dy, dz * dz)));
          }
        }
        for (int o = 32; o; o >>= 1) best = fminf(best, __shfl_xor(best, o, 64));
        if (best > H * H)
          best = expand_rings(p, cx, cy, cz, best, lane, sstarts, s);
        if (lane == 0 && best <= 2.0f) { v += best; c += 1.0f; }
      }
    }

    if (lane == 0) { wsum[wid] = v; wcnt[wid] = c; }
    __syncthreads();
    if (threadIdx.x == 0) {
      float bv = 0.f, bc = 0.f;
      for (int w = 0; w < BLOCK / 64; ++w) { bv += wsum[w]; bc += wcnt[w]; }
      if (bc != 0.f) {
        atomicAdd(&bkt[2 * (cid & 63) + 0], bv);
        atomicAdd(&bkt[2 * (cid & 63) + 1], bc);
      }
    }
  }

  // every block ticks; last one reduces the buckets and writes the output
  if (threadIdx.x == 0) {
    __threadfence();
    const unsigned prev = atomicAdd(done, 1u);
    if (prev == (unsigned)(NC - 1)) {
      float sS = 0.f, cS = 0.f;
      for (int b = 0; b < 64; ++b) {
        sS += atomicAdd(&bkt[2 * b + 0], 0.0f);   // device-scope coherent reads
        cS += atomicAdd(&bkt[2 * b + 1], 0.0f);
      }
      out[0] = sS / cS;
    }
  }
}

extern "C" void kernel_launch(void* const* d_in, const int* in_sizes, int n_in,
                              void* d_out, int out_size, void* d_ws, size_t ws_size,
                              hipStream_t stream) {
  const float* pc0 = (const float*)d_in[0];
  const float* pc1 = (const float*)d_in[1];
  float* out = (float*)d_out;

  // slab carve-up; counts1|counts0|misc contiguous -> single memset
  char* w = (char*)d_ws;
  auto nxt = [&](size_t bytes) {
    char* p = w; w += (bytes + 255) & ~(size_t)255; return p;
  };
  unsigned* counts1 = (unsigned*)nxt((size_t)NC * 4);
  unsigned* counts0 = (unsigned*)nxt((size_t)NC * 4);
  char*     misc    = nxt(1024);            // bkt[128] floats | done
  float*    bkt     = (float*)misc;
  unsigned* done    = (unsigned*)(misc + 512);
  unsigned* starts1 = (unsigned*)nxt((size_t)(NC + 1) * 4);
  unsigned* cursor1 = (unsigned*)nxt((size_t)NC * 4);
  unsigned* starts0 = (unsigned*)nxt((size_t)(NC + 1) * 4);
  unsigned* cursor0 = (unsigned*)nxt((size_t)NC * 4);
  float4* s = (float4*)nxt((size_t)NPTS * 16);
  float4* q = (float4*)nxt((size_t)NPTS * 16);

  hipMemsetAsync(counts1, 0, (size_t)2 * NC * 4 + 1024, stream);

  count_kernel<<<2 * NPTS / BLOCK, BLOCK, 0, stream>>>(pc0, pc1, counts0, counts1);
  scan_kernel<<<2, 1024, 0, stream>>>(counts0, starts0, cursor0,
                                      counts1, starts1, cursor1);
  scatter_kernel<<<2 * NPTS / BLOCK, BLOCK, 0, stream>>>(
      pc0, pc1, cursor0, cursor1, q, s);
  query_cell_kernel<<<NC, BLOCK, 0, stream>>>(q, starts0, s, starts1,
                                              bkt, done, out);
}

// Round 13
// 246.843 us; speedup vs baseline: 2.9075x; 2.9075x over previous
//
#include <hip/hip_runtime.h>

// Chamfer forward: dist0[i] = min_j ||pc0[i]-pc1[j]||^2 ; out = mean(dist0[dist0<=2])
// N = M = 65536 i.i.d. N(0,1)^3 points, fp32.
// ROUND 13: fine grid G=64 (h=0.125) + two-phase query.
//  - R12 (block-per-cell) regressed 4x: only ~2 queries/cell -> 27x duplicated LDS
//    staging. Reverted to query-per-thread (R10 = 157us baseline).
//  - h=0.25 -> 0.125 cuts E[candidates/query] 620 -> ~78 (8x less latency-bound work).
//  - Phase 1 (query_kernel): rings 0..1 only (9 preloaded CSR rows, unroll-4 ILP).
//    best <= h^2 -> exact, accumulate. Else push (idx,best) to worklist (~5%).
//  - Phase 2 (pending_kernel): one WAVE per pending query; lanes parallelize over
//    ring SEGMENTS (perimeter enumeration), so the deep-tail query (~ring 14,
//    ~1500 segments) costs ~25 serial segments/lane, not 1500.
//  - CSR via post-scatter cursor (= inclusive ends; start = ends[c-1]) - no
//    separate starts arrays. Finalize fused into pending kernel (done counter).
//  - Masked early-exit: stop expanding when best>2 and ring bound^2 >= 2 (point
//    can't pass the <=2 mask) -> bounds worst-case depth.

constexpr int   NPTS  = 65536;
constexpr int   G     = 64;
constexpr int   NC    = G * G * G;   // 262144 cells
constexpr float H     = 0.125f;
constexpr float ORG   = -4.0f;
constexpr float INVH  = 8.0f;
constexpr int   BLOCK = 256;
constexpr int   PBLOCKS = 256;       // pending kernel grid (fixed; done-counter)

__device__ __forceinline__ int cellOf(float x) {
  int c = (int)floorf((x - ORG) * INVH);
  return min(max(c, 0), G - 1);
}

__global__ __launch_bounds__(BLOCK) void count_kernel(
    const float* __restrict__ pc0, const float* __restrict__ pc1,
    unsigned* __restrict__ counts0, unsigned* __restrict__ counts1) {
  const int gid = blockIdx.x * BLOCK + threadIdx.x;
  const float* p; unsigned* cnt; int i;
  if (gid < NPTS) { p = pc1; cnt = counts1; i = gid; }
  else            { p = pc0; cnt = counts0; i = gid - NPTS; }
  const float x = p[3 * i], y = p[3 * i + 1], z = p[3 * i + 2];
  const int cid = (cellOf(z) * G + cellOf(y)) * G + cellOf(x);
  atomicAdd(&cnt[cid], 1u);
}

// Exclusive scan of NC counts into cur (two-pass per thread; PER=256 too big for regs).
__device__ void scan_one(const unsigned* __restrict__ counts,
                         unsigned* __restrict__ cur, unsigned* waveTot) {
  const int tid = threadIdx.x;
  constexpr int PER = NC / 1024;   // 256
  const int base = tid * PER;
  unsigned run = 0;
#pragma unroll 8
  for (int j = 0; j < PER; ++j) run += counts[base + j];
  unsigned inc = run;
  for (int off = 1; off < 64; off <<= 1) {
    const unsigned v = __shfl_up(inc, off, 64);
    if ((tid & 63) >= off) inc += v;
  }
  if ((tid & 63) == 63) waveTot[tid >> 6] = inc;
  __syncthreads();
  if (tid < 16) {
    unsigned w = waveTot[tid];
    for (int off = 1; off < 16; off <<= 1) {
      const unsigned v = __shfl_up(w, off, 16);
      if (tid >= off) w += v;
    }
    waveTot[tid] = w;
  }
  __syncthreads();
  const unsigned waveOff = (tid >> 6) == 0 ? 0u : waveTot[(tid >> 6) - 1];
  unsigned r = waveOff + inc - run;
  for (int j = 0; j < PER; ++j) { cur[base + j] = r; r += counts[base + j]; }
}

__global__ __launch_bounds__(1024) void scan_kernel(
    const unsigned* __restrict__ counts0, unsigned* __restrict__ cur0,
    const unsigned* __restrict__ counts1, unsigned* __restrict__ cur1) {
  __shared__ unsigned waveTot[16];
  if (blockIdx.x == 0) scan_one(counts1, cur1, waveTot);
  else                 scan_one(counts0, cur0, waveTot);
}

// After this kernel, cur[c] = CSR inclusive end of cell c (start = cur[c-1]).
__global__ __launch_bounds__(BLOCK) void scatter_kernel(
    const float* __restrict__ pc0, const float* __restrict__ pc1,
    unsigned* __restrict__ cur0, unsigned* __restrict__ cur1,
    float4* __restrict__ q, float4* __restrict__ s) {
  const int gid = blockIdx.x * BLOCK + threadIdx.x;
  const float* p; unsigned* cur; float4* dst; int i;
  if (gid < NPTS) { p = pc1; cur = cur1; dst = s; i = gid; }
  else            { p = pc0; cur = cur0; dst = q; i = gid - NPTS; }
  const float x = p[3 * i], y = p[3 * i + 1], z = p[3 * i + 2];
  const int cid = (cellOf(z) * G + cellOf(y)) * G + cellOf(x);
  const unsigned pos = atomicAdd(&cur[cid], 1u);
  dst[pos] = make_float4(x, y, z, 0.f);
}

// Phase 1: rings 0..1 per thread; push unfinished to worklist.
__global__ __launch_bounds__(BLOCK) void query_kernel(
    const float4* __restrict__ q, const unsigned* __restrict__ ends,
    const float4* __restrict__ s,
    unsigned* __restrict__ wl, float* __restrict__ wlBest,
    unsigned* __restrict__ pendCnt, float* __restrict__ bkt) {
  const int i = blockIdx.x * BLOCK + threadIdx.x;
  const float4 p = q[i];
  const int cx = cellOf(p.x), cy = cellOf(p.y), cz = cellOf(p.z);
  const int x0 = max(cx - 1, 0), x1 = min(cx + 1, G - 1);

  unsigned rs[9], re[9];
#pragma unroll
  for (int rr = 0; rr < 9; ++rr) {
    const int zz = cz + rr / 3 - 1, yy = cy + rr % 3 - 1;
    const bool ok = (zz >= 0) && (zz < G) && (yy >= 0) && (yy < G);
    const int rb = ok ? (zz * G + yy) * G : 0;
    rs[rr] = ok ? ((rb + x0) ? ends[rb + x0 - 1] : 0u) : 0u;
    re[rr] = ok ? ends[rb + x1] : 0u;
  }
  float best = 3.4e38f;
#pragma unroll
  for (int rr = 0; rr < 9; ++rr) {
#pragma unroll 4
    for (unsigned j = rs[rr]; j < re[rr]; ++j) {
      const float4 c = s[j];
      const float dx = p.x - c.x, dy = p.y - c.y, dz = p.z - c.z;
      best = fminf(best, fmaf(dx, dx, fmaf(dy, dy, dz * dz)));
    }
  }

  float v = 0.f, c = 0.f;
  if (best > H * H) {            // not provably exact -> phase 2
    const unsigned k = atomicAdd(pendCnt, 1u);
    wl[k] = (unsigned)i; wlBest[k] = best;
  } else if (best <= 2.0f) { v = best; c = 1.0f; }

  for (int o = 32; o; o >>= 1) {
    v += __shfl_down(v, o, 64);
    c += __shfl_down(c, o, 64);
  }
  __shared__ float wsum[BLOCK / 64], wcnt[BLOCK / 64];
  const int wid = threadIdx.x >> 6;
  if ((threadIdx.x & 63) == 0) { wsum[wid] = v; wcnt[wid] = c; }
  __syncthreads();
  if (threadIdx.x == 0) {
    float bv = 0.f, bc = 0.f;
    for (int w = 0; w < BLOCK / 64; ++w) { bv += wsum[w]; bc += wcnt[w]; }
    if (bc != 0.f) {
      atomicAdd(&bkt[2 * (blockIdx.x & 63) + 0], bv);
      atomicAdd(&bkt[2 * (blockIdx.x & 63) + 1], bc);
    }
  }
}

// Phase 2: one wave per pending query; lanes split ring segments.
__global__ __launch_bounds__(BLOCK) void pending_kernel(
    const float4* __restrict__ q, const unsigned* __restrict__ ends,
    const float4* __restrict__ s,
    const unsigned* __restrict__ wl, const float* __restrict__ wlBest,
    unsigned* __restrict__ pendCnt, float* __restrict__ bkt,
    unsigned* __restrict__ done, float* __restrict__ out) {
  __shared__ int snP;
  __shared__ float wsum[BLOCK / 64], wcnt[BLOCK / 64];
  __shared__ int isLast;
  __shared__ float fs[BLOCK / 64], fc[BLOCK / 64];
  if (threadIdx.x == 0) snP = (int)atomicAdd(pendCnt, 0u);
  __syncthreads();
  const int lane = threadIdx.x & 63, wid = threadIdx.x >> 6;
  const int gw = blockIdx.x * (BLOCK / 64) + wid;
  const int nW = PBLOCKS * (BLOCK / 64);
  float v = 0.f, c = 0.f;

  for (int it = gw; it < snP; it += nW) {
    const unsigned qi = wl[it];
    const float4 p = q[qi];
    const int cx = cellOf(p.x), cy = cellOf(p.y), cz = cellOf(p.z);
    float best = wlBest[it];   // wave-uniform (same address)

    for (int r = 2; r <= G; ++r) {
      const float cov = H * (float)(r - 1);     // unscanned dist lower bound
      if (best <= cov * cov) break;             // exact
      if (best > 2.0f && cov * cov >= 2.0f) break;  // masked out either way
      const int S = 8 * r + 2 * (2 * r - 1) * (2 * r - 1);
      float b = best;
      for (int sI = lane; sI < S; sI += 64) {
        int dz, dy, xa, xb;
        if (sI < 8 * r) {                       // z/y shell faces: full x rows
          if (sI < 2 * r + 1)      { dz = -r; dy = sI - r; }
          else if (sI < 4 * r + 2) { dz =  r; dy = sI - (2 * r + 1) - r; }
          else { const int t2 = sI - (4 * r + 2); dz = (t2 >> 1) - (r - 1);
                 dy = (t2 & 1) ? r : -r; }
          xa = cx - r; xb = cx + r;
        } else {                                // interior rows: x = +/- r endpoints
          const int t2 = sI - 8 * r, ci = t2 >> 1, w1 = 2 * r - 1;
          dz = ci / w1 - (r - 1); dy = ci % w1 - (r - 1);
          xa = xb = (t2 & 1) ? cx + r : cx - r;
        }
        const int zz = cz + dz, yy = cy + dy;
        if (zz < 0 || zz >= G || yy < 0 || yy >= G) continue;
        const int a = max(xa, 0), e = min(xb, G - 1);
        if (a > e) continue;
        const int rb = (zz * G + yy) * G;
        const unsigned js = (rb + a) ? ends[rb + a - 1] : 0u;
        const unsigned je = ends[rb + e];
        for (unsigned j = js; j < je; ++j) {
          const float4 cd = s[j];
          const float dx = p.x - cd.x, dyv = p.y - cd.y, dzv = p.z - cd.z;
          b = fminf(b, fmaf(dx, dx, fmaf(dyv, dyv, dzv * dzv)));
        }
      }
      for (int o = 32; o; o >>= 1) b = fminf(b, __shfl_xor(b, o, 64));
      best = b;                                 // wave-uniform again
    }
    if (lane == 0 && best <= 2.0f) { v += best; c += 1.0f; }
  }

  if (lane == 0) { wsum[wid] = v; wcnt[wid] = c; }
  __syncthreads();
  if (threadIdx.x == 0) {
    float bv = 0.f, bc = 0.f;
    for (int w = 0; w < BLOCK / 64; ++w) { bv += wsum[w]; bc += wcnt[w]; }
    if (bc != 0.f) {
      atomicAdd(&bkt[2 * (blockIdx.x & 63) + 0], bv);
      atomicAdd(&bkt[2 * (blockIdx.x & 63) + 1], bc);
    }
    __threadfence();
    isLast = (atomicAdd(done, 1u) == (unsigned)(PBLOCKS - 1));
  }
  __syncthreads();
  if (isLast) {   // parallel coherent read of the 128 bucket slots + reduce
    const float val = (threadIdx.x < 128) ? atomicAdd(&bkt[threadIdx.x], 0.0f) : 0.0f;
    float sv = (threadIdx.x & 1) ? 0.f : val;
    float cv = (threadIdx.x & 1) ? val : 0.f;
    for (int o = 32; o; o >>= 1) {
      sv += __shfl_down(sv, o, 64);
      cv += __shfl_down(cv, o, 64);
    }
    if (lane == 0) { fs[wid] = sv; fc[wid] = cv; }
    __syncthreads();
    if (threadIdx.x == 0) {
      float S = 0.f, C = 0.f;
      for (int w = 0; w < BLOCK / 64; ++w) { S += fs[w]; C += fc[w]; }
      out[0] = S / C;
    }
  }
}

extern "C" void kernel_launch(void* const* d_in, const int* in_sizes, int n_in,
                              void* d_out, int out_size, void* d_ws, size_t ws_size,
                              hipStream_t stream) {
  const float* pc0 = (const float*)d_in[0];
  const float* pc1 = (const float*)d_in[1];
  float* out = (float*)d_out;

  // slab carve-up; counts1|counts0|misc contiguous -> single memset
  char* w = (char*)d_ws;
  auto nxt = [&](size_t bytes) {
    char* p = w; w += (bytes + 255) & ~(size_t)255; return p;
  };
  unsigned* counts1 = (unsigned*)nxt((size_t)NC * 4);           // 1 MB
  unsigned* counts0 = (unsigned*)nxt((size_t)NC * 4);           // 1 MB
  char*     misc    = nxt(1024);   // bkt[128] | done | pendCnt
  float*    bkt     = (float*)misc;
  unsigned* done    = (unsigned*)(misc + 512);
  unsigned* pendCnt = (unsigned*)(misc + 516);
  unsigned* cur1    = (unsigned*)nxt((size_t)NC * 4);           // 1 MB
  unsigned* cur0    = (unsigned*)nxt((size_t)NC * 4);           // 1 MB
  float4*   s       = (float4*)nxt((size_t)NPTS * 16);          // 1 MB
  float4*   q       = (float4*)nxt((size_t)NPTS * 16);          // 1 MB
  unsigned* wl      = (unsigned*)nxt((size_t)NPTS * 4);         // 256 KB
  float*    wlBest  = (float*)nxt((size_t)NPTS * 4);            // 256 KB

  hipMemsetAsync(counts1, 0, (size_t)2 * NC * 4 + 1024, stream);

  count_kernel<<<2 * NPTS / BLOCK, BLOCK, 0, stream>>>(pc0, pc1, counts0, counts1);
  scan_kernel<<<2, 1024, 0, stream>>>(counts0, cur0, counts1, cur1);
  scatter_kernel<<<2 * NPTS / BLOCK, BLOCK, 0, stream>>>(
      pc0, pc1, cur0, cur1, q, s);
  query_kernel<<<NPTS / BLOCK, BLOCK, 0, stream>>>(q, cur1, s, wl, wlBest,
                                                   pendCnt, bkt);
  pending_kernel<<<PBLOCKS, BLOCK, 0, stream>>>(q, cur1, s, wl, wlBest,
                                                pendCnt, bkt, done, out);
}

// Round 14
// 157.046 us; speedup vs baseline: 4.5699x; 1.5718x over previous
//
#include <hip/hip_runtime.h>

// Chamfer forward: dist0[i] = min_j ||pc0[i]-pc1[j]||^2 ; out = mean(dist0[dist0<=2])
// N = M = 65536 i.i.d. N(0,1)^3 points, fp32.
// Spatial grid G=64 (h=0.125), counting sort, two-phase query (R13: 246us).
// ROUND 14: the single-block-per-array scan was the #1 dispatch (100.7us,
// VALUBusy 0.02%, 2 blocks = 2 CUs). Replaced with a 3-phase multi-block scan:
//   A) scan_partial: 128 blocks/array, block-reduce chunk sums      (~4us)
//   B) scan_mid:     1 block scans the 2x128 partials               (~2us)
//   C) scan_final:   128 blocks/array, block scan + offset -> cur   (~6us)
// Query/pending/count/scatter unchanged from R13.

constexpr int   NPTS  = 65536;
constexpr int   G     = 64;
constexpr int   NC    = G * G * G;   // 262144 cells
constexpr float H     = 0.125f;
constexpr float ORG   = -4.0f;
constexpr float INVH  = 8.0f;
constexpr int   BLOCK = 256;
constexpr int   PBLOCKS = 256;       // pending kernel grid (fixed; done-counter)
constexpr int   SB    = 128;         // scan blocks per array
constexpr int   CHUNK = NC / SB;     // 2048 counts per scan block (2/thread)

__device__ __forceinline__ int cellOf(float x) {
  int c = (int)floorf((x - ORG) * INVH);
  return min(max(c, 0), G - 1);
}

__global__ __launch_bounds__(BLOCK) void count_kernel(
    const float* __restrict__ pc0, const float* __restrict__ pc1,
    unsigned* __restrict__ counts0, unsigned* __restrict__ counts1) {
  const int gid = blockIdx.x * BLOCK + threadIdx.x;
  const float* p; unsigned* cnt; int i;
  if (gid < NPTS) { p = pc1; cnt = counts1; i = gid; }
  else            { p = pc0; cnt = counts0; i = gid - NPTS; }
  const float x = p[3 * i], y = p[3 * i + 1], z = p[3 * i + 2];
  const int cid = (cellOf(z) * G + cellOf(y)) * G + cellOf(x);
  atomicAdd(&cnt[cid], 1u);
}

// Phase A: per-block partial sums. grid = (SB, 2); y=0 -> counts1, y=1 -> counts0.
__global__ __launch_bounds__(1024) void scan_partial_kernel(
    const unsigned* __restrict__ counts0, const unsigned* __restrict__ counts1,
    unsigned* __restrict__ partials) {
  const unsigned* counts = blockIdx.y ? counts0 : counts1;
  const int base = blockIdx.x * CHUNK + threadIdx.x * 2;
  unsigned sum = counts[base] + counts[base + 1];
  for (int o = 32; o; o >>= 1) sum += __shfl_down(sum, o, 64);
  __shared__ unsigned ws[16];
  if ((threadIdx.x & 63) == 0) ws[threadIdx.x >> 6] = sum;
  __syncthreads();
  if (threadIdx.x == 0) {
    unsigned t = 0;
    for (int w = 0; w < 16; ++w) t += ws[w];
    partials[blockIdx.y * SB + blockIdx.x] = t;
  }
}

// Phase B: one block exclusively scans both 128-entry partial arrays.
__global__ __launch_bounds__(256) void scan_mid_kernel(
    unsigned* __restrict__ partials) {
  const int tid = threadIdx.x;          // 0..255
  const int g   = tid >> 7;             // 0 -> array1 half, 1 -> array0 half
  const int li  = tid & 127;
  const unsigned v = partials[g * SB + li];
  unsigned inc = v;
  for (int o = 1; o < 64; o <<= 1) {
    const unsigned t = __shfl_up(inc, o, 64);
    if ((tid & 63) >= o) inc += t;
  }
  __shared__ unsigned wt[4];            // 4 waves: 0,1 -> g=0; 2,3 -> g=1
  if ((tid & 63) == 63) wt[tid >> 6] = inc;
  __syncthreads();
  const unsigned woff = ((tid >> 6) & 1) ? wt[g << 1] : 0u;
  partials[g * SB + li] = woff + inc - v;   // exclusive block offset
}

// Phase C: block-level exclusive scan + block offset -> cur (CSR starts).
__global__ __launch_bounds__(1024) void scan_final_kernel(
    const unsigned* __restrict__ counts0, unsigned* __restrict__ cur0,
    const unsigned* __restrict__ counts1, unsigned* __restrict__ cur1,
    const unsigned* __restrict__ partials) {
  const unsigned* counts = blockIdx.y ? counts0 : counts1;
  unsigned* cur          = blockIdx.y ? cur0    : cur1;
  const int tid = threadIdx.x;
  const int base = blockIdx.x * CHUNK + tid * 2;
  const unsigned a = counts[base], b = counts[base + 1];
  const unsigned tsum = a + b;
  unsigned inc = tsum;
  for (int o = 1; o < 64; o <<= 1) {
    const unsigned t = __shfl_up(inc, o, 64);
    if ((tid & 63) >= o) inc += t;
  }
  __shared__ unsigned wt[16];
  if ((tid & 63) == 63) wt[tid >> 6] = inc;
  __syncthreads();
  if (tid < 16) {
    unsigned w = wt[tid];
    for (int o = 1; o < 16; o <<= 1) {
      const unsigned t = __shfl_up(w, o, 16);
      if (tid >= o) w += t;
    }
    wt[tid] = w;
  }
  __syncthreads();
  const unsigned woff = (tid >> 6) ? wt[(tid >> 6) - 1] : 0u;
  const unsigned off =
      partials[blockIdx.y * SB + blockIdx.x] + woff + inc - tsum;
  cur[base] = off;
  cur[base + 1] = off + a;
}

// After scatter, cur[c] = CSR inclusive end of cell c (start = cur[c-1]).
__global__ __launch_bounds__(BLOCK) void scatter_kernel(
    const float* __restrict__ pc0, const float* __restrict__ pc1,
    unsigned* __restrict__ cur0, unsigned* __restrict__ cur1,
    float4* __restrict__ q, float4* __restrict__ s) {
  const int gid = blockIdx.x * BLOCK + threadIdx.x;
  const float* p; unsigned* cur; float4* dst; int i;
  if (gid < NPTS) { p = pc1; cur = cur1; dst = s; i = gid; }
  else            { p = pc0; cur = cur0; dst = q; i = gid - NPTS; }
  const float x = p[3 * i], y = p[3 * i + 1], z = p[3 * i + 2];
  const int cid = (cellOf(z) * G + cellOf(y)) * G + cellOf(x);
  const unsigned pos = atomicAdd(&cur[cid], 1u);
  dst[pos] = make_float4(x, y, z, 0.f);
}

// Phase 1: rings 0..1 per thread; push unfinished to worklist.
__global__ __launch_bounds__(BLOCK) void query_kernel(
    const float4* __restrict__ q, const unsigned* __restrict__ ends,
    const float4* __restrict__ s,
    unsigned* __restrict__ wl, float* __restrict__ wlBest,
    unsigned* __restrict__ pendCnt, float* __restrict__ bkt) {
  const int i = blockIdx.x * BLOCK + threadIdx.x;
  const float4 p = q[i];
  const int cx = cellOf(p.x), cy = cellOf(p.y), cz = cellOf(p.z);
  const int x0 = max(cx - 1, 0), x1 = min(cx + 1, G - 1);

  unsigned rs[9], re[9];
#pragma unroll
  for (int rr = 0; rr < 9; ++rr) {
    const int zz = cz + rr / 3 - 1, yy = cy + rr % 3 - 1;
    const bool ok = (zz >= 0) && (zz < G) && (yy >= 0) && (yy < G);
    const int rb = ok ? (zz * G + yy) * G : 0;
    rs[rr] = ok ? ((rb + x0) ? ends[rb + x0 - 1] : 0u) : 0u;
    re[rr] = ok ? ends[rb + x1] : 0u;
  }
  float best = 3.4e38f;
#pragma unroll
  for (int rr = 0; rr < 9; ++rr) {
#pragma unroll 4
    for (unsigned j = rs[rr]; j < re[rr]; ++j) {
      const float4 c = s[j];
      const float dx = p.x - c.x, dy = p.y - c.y, dz = p.z - c.z;
      best = fminf(best, fmaf(dx, dx, fmaf(dy, dy, dz * dz)));
    }
  }

  float v = 0.f, c = 0.f;
  if (best > H * H) {            // not provably exact -> phase 2
    const unsigned k = atomicAdd(pendCnt, 1u);
    wl[k] = (unsigned)i; wlBest[k] = best;
  } else if (best <= 2.0f) { v = best; c = 1.0f; }

  for (int o = 32; o; o >>= 1) {
    v += __shfl_down(v, o, 64);
    c += __shfl_down(c, o, 64);
  }
  __shared__ float wsum[BLOCK / 64], wcnt[BLOCK / 64];
  const int wid = threadIdx.x >> 6;
  if ((threadIdx.x & 63) == 0) { wsum[wid] = v; wcnt[wid] = c; }
  __syncthreads();
  if (threadIdx.x == 0) {
    float bv = 0.f, bc = 0.f;
    for (int w = 0; w < BLOCK / 64; ++w) { bv += wsum[w]; bc += wcnt[w]; }
    if (bc != 0.f) {
      atomicAdd(&bkt[2 * (blockIdx.x & 63) + 0], bv);
      atomicAdd(&bkt[2 * (blockIdx.x & 63) + 1], bc);
    }
  }
}

// Phase 2: one wave per pending query; lanes split ring segments.
__global__ __launch_bounds__(BLOCK) void pending_kernel(
    const float4* __restrict__ q, const unsigned* __restrict__ ends,
    const float4* __restrict__ s,
    const unsigned* __restrict__ wl, const float* __restrict__ wlBest,
    unsigned* __restrict__ pendCnt, float* __restrict__ bkt,
    unsigned* __restrict__ done, float* __restrict__ out) {
  __shared__ int snP;
  __shared__ float wsum[BLOCK / 64], wcnt[BLOCK / 64];
  __shared__ int isLast;
  __shared__ float fs[BLOCK / 64], fc[BLOCK / 64];
  if (threadIdx.x == 0) snP = (int)atomicAdd(pendCnt, 0u);
  __syncthreads();
  const int lane = threadIdx.x & 63, wid = threadIdx.x >> 6;
  const int gw = blockIdx.x * (BLOCK / 64) + wid;
  const int nW = PBLOCKS * (BLOCK / 64);
  float v = 0.f, c = 0.f;

  for (int it = gw; it < snP; it += nW) {
    const unsigned qi = wl[it];
    const float4 p = q[qi];
    const int cx = cellOf(p.x), cy = cellOf(p.y), cz = cellOf(p.z);
    float best = wlBest[it];   // wave-uniform (same address)

    for (int r = 2; r <= G; ++r) {
      const float cov = H * (float)(r - 1);     // unscanned dist lower bound
      if (best <= cov * cov) break;             // exact
      if (best > 2.0f && cov * cov >= 2.0f) break;  // masked out either way
      const int S = 8 * r + 2 * (2 * r - 1) * (2 * r - 1);
      float b = best;
      for (int sI = lane; sI < S; sI += 64) {
        int dz, dy, xa, xb;
        if (sI < 8 * r) {                       // z/y shell faces: full x rows
          if (sI < 2 * r + 1)      { dz = -r; dy = sI - r; }
          else if (sI < 4 * r + 2) { dz =  r; dy = sI - (2 * r + 1) - r; }
          else { const int t2 = sI - (4 * r + 2); dz = (t2 >> 1) - (r - 1);
                 dy = (t2 & 1) ? r : -r; }
          xa = cx - r; xb = cx + r;
        } else {                                // interior rows: x = +/- r endpoints
          const int t2 = sI - 8 * r, ci = t2 >> 1, w1 = 2 * r - 1;
          dz = ci / w1 - (r - 1); dy = ci % w1 - (r - 1);
          xa = xb = (t2 & 1) ? cx + r : cx - r;
        }
        const int zz = cz + dz, yy = cy + dy;
        if (zz < 0 || zz >= G || yy < 0 || yy >= G) continue;
        const int a = max(xa, 0), e = min(xb, G - 1);
        if (a > e) continue;
        const int rb = (zz * G + yy) * G;
        const unsigned js = (rb + a) ? ends[rb + a - 1] : 0u;
        const unsigned je = ends[rb + e];
        for (unsigned j = js; j < je; ++j) {
          const float4 cd = s[j];
          const float dx = p.x - cd.x, dyv = p.y - cd.y, dzv = p.z - cd.z;
          b = fminf(b, fmaf(dx, dx, fmaf(dyv, dyv, dzv * dzv)));
        }
      }
      for (int o = 32; o; o >>= 1) b = fminf(b, __shfl_xor(b, o, 64));
      best = b;                                 // wave-uniform again
    }
    if (lane == 0 && best <= 2.0f) { v += best; c += 1.0f; }
  }

  if (lane == 0) { wsum[wid] = v; wcnt[wid] = c; }
  __syncthreads();
  if (threadIdx.x == 0) {
    float bv = 0.f, bc = 0.f;
    for (int w = 0; w < BLOCK / 64; ++w) { bv += wsum[w]; bc += wcnt[w]; }
    if (bc != 0.f) {
      atomicAdd(&bkt[2 * (blockIdx.x & 63) + 0], bv);
      atomicAdd(&bkt[2 * (blockIdx.x & 63) + 1], bc);
    }
    __threadfence();
    isLast = (atomicAdd(done, 1u) == (unsigned)(PBLOCKS - 1));
  }
  __syncthreads();
  if (isLast) {   // parallel coherent read of the 128 bucket slots + reduce
    const float val = (threadIdx.x < 128) ? atomicAdd(&bkt[threadIdx.x], 0.0f) : 0.0f;
    float sv = (threadIdx.x & 1) ? 0.f : val;
    float cv = (threadIdx.x & 1) ? val : 0.f;
    for (int o = 32; o; o >>= 1) {
      sv += __shfl_down(sv, o, 64);
      cv += __shfl_down(cv, o, 64);
    }
    if (lane == 0) { fs[wid] = sv; fc[wid] = cv; }
    __syncthreads();
    if (threadIdx.x == 0) {
      float S = 0.f, C = 0.f;
      for (int w = 0; w < BLOCK / 64; ++w) { S += fs[w]; C += fc[w]; }
      out[0] = S / C;
    }
  }
}

extern "C" void kernel_launch(void* const* d_in, const int* in_sizes, int n_in,
                              void* d_out, int out_size, void* d_ws, size_t ws_size,
                              hipStream_t stream) {
  const float* pc0 = (const float*)d_in[0];
  const float* pc1 = (const float*)d_in[1];
  float* out = (float*)d_out;

  // slab carve-up; counts1|counts0|misc contiguous -> single memset
  char* w = (char*)d_ws;
  auto nxt = [&](size_t bytes) {
    char* p = w; w += (bytes + 255) & ~(size_t)255; return p;
  };
  unsigned* counts1  = (unsigned*)nxt((size_t)NC * 4);           // 1 MB
  unsigned* counts0  = (unsigned*)nxt((size_t)NC * 4);           // 1 MB
  char*     misc     = nxt(1024);   // bkt[128] | done | pendCnt
  float*    bkt      = (float*)misc;
  unsigned* done     = (unsigned*)(misc + 512);
  unsigned* pendCnt  = (unsigned*)(misc + 516);
  unsigned* partials = (unsigned*)nxt((size_t)2 * SB * 4);       // 1 KB
  unsigned* cur1     = (unsigned*)nxt((size_t)NC * 4);           // 1 MB
  unsigned* cur0     = (unsigned*)nxt((size_t)NC * 4);           // 1 MB
  float4*   s        = (float4*)nxt((size_t)NPTS * 16);          // 1 MB
  float4*   q        = (float4*)nxt((size_t)NPTS * 16);          // 1 MB
  unsigned* wl       = (unsigned*)nxt((size_t)NPTS * 4);         // 256 KB
  float*    wlBest   = (float*)nxt((size_t)NPTS * 4);            // 256 KB

  hipMemsetAsync(counts1, 0, (size_t)2 * NC * 4 + 1024, stream);

  count_kernel<<<2 * NPTS / BLOCK, BLOCK, 0, stream>>>(pc0, pc1, counts0, counts1);
  scan_partial_kernel<<<dim3(SB, 2), 1024, 0, stream>>>(counts0, counts1, partials);
  scan_mid_kernel<<<1, 256, 0, stream>>>(partials);
  scan_final_kernel<<<dim3(SB, 2), 1024, 0, stream>>>(counts0, cur0,
                                                      counts1, cur1, partials);
  scatter_kernel<<<2 * NPTS / BLOCK, BLOCK, 0, stream>>>(
      pc0, pc1, cur0, cur1, q, s);
  query_kernel<<<NPTS / BLOCK, BLOCK, 0, stream>>>(q, cur1, s, wl, wlBest,
                                                   pendCnt, bkt);
  pending_kernel<<<PBLOCKS, BLOCK, 0, stream>>>(q, cur1, s, wl, wlBest,
                                                pendCnt, bkt, done, out);
}